// Round 6
// baseline (8268.224 us; speedup 1.0000x reference)
//
#include <hip/hip_runtime.h>
#include <stdint.h>
#include <stddef.h>

typedef __attribute__((ext_vector_type(8))) short bf16x8;
typedef __attribute__((ext_vector_type(4))) float f32x4;

#define NBLK 128
#define NTHR 512          // 8 waves: 2 waves/SIMD TLP, K split 8 ways
#define S_LEN 512
#define HD   1024
#define IDIM 512

#define MFMA16 __builtin_amdgcn_mfma_f32_16x16x32_bf16

__device__ __forceinline__ float bf2f(uint16_t u){
  union { uint32_t i; float f; } v; v.i = ((uint32_t)u) << 16; return v.f;
}
__device__ __forceinline__ uint16_t f2bf(float f){
  union { float f; uint32_t i; } v; v.f = f;
  uint32_t r = v.i + 0x7fffu + ((v.i >> 16) & 1u);   // round-nearest-even
  return (uint16_t)(r >> 16);
}
__device__ __forceinline__ float sigm(float x){ return 1.0f / (1.0f + __expf(-x)); }
__device__ __forceinline__ float tanh_(float x){
  float t = fminf(fmaxf(2.0f * x, -30.0f), 30.0f);
  float e = __expf(t);
  return (e - 1.0f) / (e + 1.0f);
}

// Split 8 consecutive fp32 (memory) into bf16 hi + lo (residual) fragments.
__device__ __forceinline__ void split8(const float* p, bf16x8& hi8, bf16x8& lo8){
  const float4 a = *(const float4*)p;
  const float4 b = *(const float4*)(p + 4);
  float v[8] = {a.x, a.y, a.z, a.w, b.x, b.y, b.z, b.w};
  #pragma unroll
  for (int j = 0; j < 8; ++j){
    uint16_t h = f2bf(v[j]);
    hi8[j] = (short)h;
    lo8[j] = (short)f2bf(v[j] - bf2f(h));
  }
}
// Register-input variant (for asm-loaded h rows).
__device__ __forceinline__ void split8v(const f32x4& a, const f32x4& b,
                                        bf16x8& hi8, bf16x8& lo8){
  float v[8] = {a[0], a[1], a[2], a[3], b[0], b[1], b[2], b[3]};
  #pragma unroll
  for (int j = 0; j < 8; ++j){
    uint16_t h = f2bf(v[j]);
    hi8[j] = (short)h;
    lo8[j] = (short)f2bf(v[j] - bf2f(h));
  }
}

// Normal CACHED 16B load (L1/L2/LLC). Safe for h-reads because every out
// address is written exactly once and never read before its step's flag —
// no stale line can exist. volatile => program-order issue, counted in vmcnt.
__device__ __forceinline__ void nload16(const float* p, f32x4& d){
  asm volatile("global_load_dwordx4 %0, %1, off" : "=v"(d) : "v"(p));
}
// Write-through publish store: visible at the LLC coherence point once its
// vmcnt retires (validated by the r2 flag protocol).
__device__ __forceinline__ void fstore_sc(float* p, float v){
  asm volatile("global_store_dword %0, %1, off sc0 sc1" :: "v"(p), "v"(v) : "memory");
}

#define WAITV(n) do { \
    asm volatile("s_waitcnt vmcnt(" #n ")" ::: "memory"); \
    __builtin_amdgcn_sched_barrier(0); \
  } while (0)

// Persistent LSTM. 128 blocks x 8 waves; block f owns h-cols [8f,8f+8).
// Gate tiles (N=16): tile0 = [H1|H2] (forget|input), tile1 = [H3|H4] (cand|out).
// K split across 8 waves (h:128 each, x:64 each); weights in VGPRs as bf16
// hi+lo pairs; A*W via 3 MFMAs (Ahi*Whi + Alo*Whi + Ahi*Wlo).
//
// Round-6: h is broadcast THROUGH `out` itself. out[batch][t][col] is written
// exactly once (single-writer per address) => consumers may use normal
// L2-CACHED loads with no staleness hazard: no (batch,t) line is ever touched
// before step-t's flag, and kernel-boundary invalidation covers graph replays.
// This lets the 16 blocks of each XCD share one 256KB L2 copy of h_t instead
// of 16 independent LLC pulls (the suspected 32MB/step LLC-fabric floor that
// made r2/r3 step time invariant to scheduling). The hbhi/hblo side buffers
// and their publish stores are deleted; the out store (sc0 sc1 write-through)
// IS the publish. Consumers split fp32->bf16 hi/lo in-register (identical
// f2bf math as the old producer-side split => bit-identical results).
__global__ void __launch_bounds__(NTHR, 2) lstm_persist(
    const float* __restrict__ x,
    const float* __restrict__ X1, const float* __restrict__ H1, const float* __restrict__ b1,
    const float* __restrict__ X2, const float* __restrict__ H2, const float* __restrict__ b2,
    const float* __restrict__ X3, const float* __restrict__ H3, const float* __restrict__ b3,
    const float* __restrict__ X4, const float* __restrict__ H4, const float* __restrict__ b4,
    float* __restrict__ out, int* done)
{
  __shared__ float part[8][64][36];   // stride 36: 2-way bank alias only
  const int tid  = threadIdx.x;
  const int w    = tid >> 6;          // wave 0..7
  const int L    = tid & 63;
  const int c    = L & 15;            // MFMA n / A-row-in-tile
  const int quad = L >> 4;
  const int cc   = c & 7;
  const int f    = blockIdx.x;
  const int colh = f * 8 + cc;        // owned h-column
  const bool hiHalf = (c >= 8);

  const float* W0 = hiHalf ? H2 : H1;
  const float* W1 = hiHalf ? H4 : H3;
  const float* V0 = hiHalf ? X2 : X1;
  const float* V1 = hiHalf ? X4 : X3;
  const float bias0 = (hiHalf ? b2 : b1)[colh];
  const float bias1 = (hiHalf ? b4 : b3)[colh];

  // --- one-time: weight fragments (B layout: n = lane&15, k = quad*8 + j) ---
  bf16x8 BhH0[4], BhL0[4], BhH1[4], BhL1[4];
  #pragma unroll
  for (int kk = 0; kk < 4; ++kk){
    const int kb = w*128 + kk*32 + quad*8;
    bf16x8 h0, l0, h1, l1;
    #pragma unroll
    for (int j = 0; j < 8; ++j){
      float w0 = W0[(size_t)(kb + j)*HD + colh];
      uint16_t a = f2bf(w0); h0[j] = (short)a; l0[j] = (short)f2bf(w0 - bf2f(a));
      float w1 = W1[(size_t)(kb + j)*HD + colh];
      uint16_t b_ = f2bf(w1); h1[j] = (short)b_; l1[j] = (short)f2bf(w1 - bf2f(b_));
    }
    BhH0[kk] = h0; BhL0[kk] = l0; BhH1[kk] = h1; BhL1[kk] = l1;
  }
  bf16x8 BxH0[2], BxL0[2], BxH1[2], BxL1[2];
  #pragma unroll
  for (int kk = 0; kk < 2; ++kk){
    const int kb = w*64 + kk*32 + quad*8;
    bf16x8 h0, l0, h1, l1;
    #pragma unroll
    for (int j = 0; j < 8; ++j){
      float w0 = V0[(size_t)(kb + j)*HD + colh];
      uint16_t a = f2bf(w0); h0[j] = (short)a; l0[j] = (short)f2bf(w0 - bf2f(a));
      float w1 = V1[(size_t)(kb + j)*HD + colh];
      uint16_t b_ = f2bf(w1); h1[j] = (short)b_; l1[j] = (short)f2bf(w1 - bf2f(b_));
    }
    BxH0[kk] = h0; BxL0[kk] = l0; BxH1[kk] = h1; BxL1[kk] = l1;
  }

  float cst[2] = {0.f, 0.f};

  #pragma unroll 1
  for (int t = 0; t < S_LEN; ++t){
    f32x4 acc0[4], acc1[4];
    #pragma unroll
    for (int m = 0; m < 4; ++m){
      acc0[m] = (f32x4){0.f,0.f,0.f,0.f};
      acc1[m] = (f32x4){0.f,0.f,0.f,0.f};
    }

    // ---- x-phase: x_t @ Xcat slice (h-independent; overlaps the poll tail
    //      of other blocks' publishes — r2 placement) ----
    #pragma unroll
    for (int kk = 0; kk < 2; ++kk){
      #pragma unroll
      for (int m = 0; m < 4; ++m){
        const float* xp = x + ((size_t)(16*m + c)*S_LEN + t)*IDIM + w*64 + kk*32 + quad*8;
        bf16x8 Ah, Al; split8(xp, Ah, Al);
        acc0[m] = MFMA16(Ah, BxH0[kk], acc0[m], 0, 0, 0);
        acc0[m] = MFMA16(Al, BxH0[kk], acc0[m], 0, 0, 0);
        acc0[m] = MFMA16(Ah, BxL0[kk], acc0[m], 0, 0, 0);
        acc1[m] = MFMA16(Ah, BxH1[kk], acc1[m], 0, 0, 0);
        acc1[m] = MFMA16(Al, BxH1[kk], acc1[m], 0, 0, 0);
        acc1[m] = MFMA16(Ah, BxL1[kk], acc1[m], 0, 0, 0);
      }
    }

    if (t > 0){
      // ---- wait: all blocks must have published h_t = out[:, t-1, :] ----
      if (tid < NBLK){
        while (__hip_atomic_load(&done[tid*32], __ATOMIC_RELAXED, __HIP_MEMORY_SCOPE_AGENT) < t)
          __builtin_amdgcn_s_sleep(2);
      }
      __syncthreads();

      // ---- h-phase: cached loads from out[:, t-1, :], counted-vmcnt pipe,
      //      in-register fp32->bf16 hi/lo split feeding 3-MFMA pairs ----
      f32x4 raw[2][4][2];   // [buf][kk][half-of-8-floats]
      #define H_PTR(m, kk) (out + ((size_t)(16*(m) + c)*S_LEN + (t-1))*HD \
                                + w*128 + (kk)*32 + quad*8)
      #define ISSUE_M(buf, m) do { \
        _Pragma("unroll") \
        for (int kk = 0; kk < 4; ++kk){ \
          nload16(H_PTR(m, kk),     raw[buf][kk][0]); \
          nload16(H_PTR(m, kk) + 4, raw[buf][kk][1]); \
        } } while(0)

      // drain leftovers (x-phase loads, prev publish/flag stores) so the
      // counted waits below are exact and wave-uniform
      WAITV(0);
      ISSUE_M(0, 0);
      #pragma unroll
      for (int m = 0; m < 4; ++m){
        const int buf = m & 1;
        if (m < 3){
          ISSUE_M(buf ^ 1, m + 1);
          WAITV(8);         // batch m's 8 loads retired; batch m+1 in flight
        } else {
          WAITV(0);
        }
        #pragma unroll
        for (int kk = 0; kk < 4; ++kk){
          bf16x8 Ah, Al;
          split8v(raw[buf][kk][0], raw[buf][kk][1], Ah, Al);
          acc0[m] = MFMA16(Ah, BhH0[kk], acc0[m], 0, 0, 0);
          acc0[m] = MFMA16(Al, BhH0[kk], acc0[m], 0, 0, 0);
          acc0[m] = MFMA16(Ah, BhL0[kk], acc0[m], 0, 0, 0);
          acc1[m] = MFMA16(Ah, BhH1[kk], acc1[m], 0, 0, 0);
          acc1[m] = MFMA16(Al, BhH1[kk], acc1[m], 0, 0, 0);
          acc1[m] = MFMA16(Ah, BhL1[kk], acc1[m], 0, 0, 0);
        }
      }
      #undef ISSUE_M
      #undef H_PTR
    }

    // ---- stash partials (C/D: col = lane&15, row = quad*4 + reg) ----
    #pragma unroll
    for (int m = 0; m < 4; ++m){
      #pragma unroll
      for (int r = 0; r < 4; ++r){
        part[w][16*m + quad*4 + r][c]      = acc0[m][r];
        part[w][16*m + quad*4 + r][16 + c] = acc1[m][r];
      }
    }
    __syncthreads();

    // ---- cross-wave K-reduction; wave w handles batch rows [8w,8w+8) ----
    float g0[2], g1[2];
    #pragma unroll
    for (int r2 = 0; r2 < 2; ++r2){
      const int row = 8*w + quad*2 + r2;
      float a = bias0, b = bias1;
      #pragma unroll
      for (int ww = 0; ww < 8; ++ww){
        a += part[ww][row][c];
        b += part[ww][row][16 + c];
      }
      g0[r2] = a; g1[r2] = b;
    }

    // ---- gates (lane c<8 holds forget/cand; partner c+8 holds input/output) ----
    float hv[2];
    #pragma unroll
    for (int r2 = 0; r2 < 2; ++r2){
      float gf = g0[r2];
      float gi = __shfl_xor(g0[r2], 8, 64);
      float gc = g1[r2];
      float go = __shfl_xor(g1[r2], 8, 64);
      float cn = cst[r2] * sigm(gf) + sigm(gi) * tanh_(gc);
      cst[r2] = cn;
      hv[r2] = tanh_(cn) * sigm(go);
    }

    // ---- publish: the out store IS the h broadcast (write-through) ----
    if (!hiHalf){
      #pragma unroll
      for (int r2 = 0; r2 < 2; ++r2){
        const int batch = 8*w + quad*2 + r2;
        fstore_sc(&out[(size_t)(batch*S_LEN + t)*HD + colh], hv[r2]);
      }
    }

    // drain publish stores to the LLC coherence point, converge, flag
    asm volatile("s_waitcnt vmcnt(0)" ::: "memory");
    __syncthreads();
    if (tid == 0)
      __hip_atomic_store(&done[f*32], t + 1, __ATOMIC_RELAXED, __HIP_MEMORY_SCOPE_AGENT);
  }
}

extern "C" void kernel_launch(void* const* d_in, const int* in_sizes, int n_in,
                              void* d_out, int out_size, void* d_ws, size_t ws_size,
                              hipStream_t stream) {
  const float* x  = (const float*)d_in[0];
  const float* X1 = (const float*)d_in[1];
  const float* H1 = (const float*)d_in[2];
  const float* b1 = (const float*)d_in[3];
  const float* X2 = (const float*)d_in[4];
  const float* H2 = (const float*)d_in[5];
  const float* b2 = (const float*)d_in[6];
  const float* X3 = (const float*)d_in[7];
  const float* H3 = (const float*)d_in[8];
  const float* b3 = (const float*)d_in[9];
  const float* X4 = (const float*)d_in[10];
  const float* H4 = (const float*)d_in[11];
  const float* b4 = (const float*)d_in[12];
  float* out = (float*)d_out;

  // ws: done[128] flags @128B stride only — h travels through `out` itself
  int* done = (int*)d_ws;
  hipMemsetAsync(d_ws, 0, 16384, stream);

  hipLaunchKernelGGL(lstm_persist, dim3(NBLK), dim3(NTHR), 0, stream,
                     x, X1, H1, b1, X2, H2, b2, X3, H3, b3, X4, H4, b4,
                     out, done);
}